// Round 1
// baseline (1356.194 us; speedup 1.0000x reference)
//
#include <hip/hip_runtime.h>

typedef unsigned short u16;
typedef __attribute__((ext_vector_type(8))) short bf16x8;
typedef __attribute__((ext_vector_type(4))) float f32x4;

#define NV 50257
#define NVP 50304
#define NR 960          // 60*16 rows
#define NCB 786         // 50304/64 col blocks
#define TLQ 6

__device__ __forceinline__ u16 f2b(float x) {
    union { float f; unsigned u; } v; v.f = x;
    unsigned r = v.u + 0x7FFFu + ((v.u >> 16) & 1u);
    return (u16)(r >> 16);
}
__device__ __forceinline__ float b2f(u16 h) {
    union { unsigned u; float f; } v; v.u = ((unsigned)h) << 16;
    return v.f;
}
__device__ __forceinline__ float sigm(float x) { return 1.f / (1.f + __expf(-x)); }

// ---------------- prep kernels ----------------
__global__ void conv_k(const float* __restrict__ in, u16* __restrict__ out, int n) {
    int i = blockIdx.x * 256 + threadIdx.x;
    if (i < n) out[i] = f2b(in[i]);
}
__global__ void embpad_k(const float* __restrict__ W_emb, u16* __restrict__ out) {
    int i = blockIdx.x * 256 + threadIdx.x;
    if (i < NVP * 128) out[i] = (i < NV * 128) ? f2b(W_emb[i]) : (u16)0;
}
__global__ void attnT_k(const float* __restrict__ We, const float* __restrict__ Wd, u16* __restrict__ out) {
    int i = blockIdx.x * 256 + threadIdx.x;
    if (i < 1024 * 512) {
        int n = i >> 9, k = i & 511;
        float v = (n < 512) ? We[k * 512 + n] : Wd[k * 512 + (n - 512)];
        out[i] = f2b(v);
    }
}
__global__ void projT_k(const float* __restrict__ Wp, u16* __restrict__ out) {
    int i = blockIdx.x * 256 + threadIdx.x;
    if (i < 1536 * 128) {
        int k = i >> 7, e = i & 127;
        out[i] = f2b(Wp[e * 1536 + k]);
    }
}
__global__ void gather_k(const float* __restrict__ W_emb, const int* __restrict__ tgt, u16* __restrict__ out) {
    int i = blockIdx.x * 256 + threadIdx.x;
    if (i < NR * 128) {
        int r = i >> 7, e = i & 127;
        out[i] = f2b(W_emb[(size_t)tgt[r] * 128 + e]);
    }
}
__global__ void init_k(const float* __restrict__ c0, const float* __restrict__ h0,
                       float* __restrict__ c_state, u16* __restrict__ hb0) {
    int i = blockIdx.x * 256 + threadIdx.x;
    if (i < 8192) { c_state[i] = c0[i]; hb0[i] = f2b(h0[i]); }
}

// ---------------- generic 64x64 bf16 MFMA GEMM  C = A(MxK) * B(NxK)^T ----------------
// MODE 0: outF[row*ldC+col] = acc + bias1[col] + bias2[col]
// MODE 1: outB[row*ldC+col] = bf16(tanh(acc))
// MODE 2: streaming LSE partials over valid cols (v = vc0+col < NV), logit = acc + bias1[v]
template<int MODE>
__global__ __launch_bounds__(256) void gemm_k(
    const u16* __restrict__ A, const u16* __restrict__ Bm,
    int K, int ldC,
    float* __restrict__ outF, u16* __restrict__ outB,
    const float* __restrict__ bias1, const float* __restrict__ bias2,
    float* __restrict__ pmax, float* __restrict__ psum, int vc0)
{
    __shared__ u16 Al[64 * 40];
    __shared__ u16 Bl[64 * 40];
    const int tid = threadIdx.x;
    const int wv = tid >> 6, ln = tid & 63;
    const int bn = blockIdx.x, bm = blockIdx.y;
    const int srow = tid >> 2;
    const int skc = (tid & 3) * 8;
    const size_t aoff = (size_t)(bm * 64 + srow) * K + skc;
    const size_t boff = (size_t)(bn * 64 + srow) * K + skc;
    f32x4 zz = {0.f, 0.f, 0.f, 0.f};
    f32x4 acc[4];
#pragma unroll
    for (int t = 0; t < 4; t++) acc[t] = zz;
    const int fra = (wv * 16 + (ln & 15)) * 40 + (ln >> 4) * 8;

    for (int kb = 0; kb < K; kb += 32) {
        *(bf16x8*)&Al[srow * 40 + skc] = *(const bf16x8*)&A[aoff + kb];
        *(bf16x8*)&Bl[srow * 40 + skc] = *(const bf16x8*)&Bm[boff + kb];
        __syncthreads();
        bf16x8 af = *(const bf16x8*)&Al[fra];
#pragma unroll
        for (int t = 0; t < 4; t++) {
            bf16x8 bfr = *(const bf16x8*)&Bl[(t * 16 + (ln & 15)) * 40 + (ln >> 4) * 8];
            acc[t] = __builtin_amdgcn_mfma_f32_16x16x32_bf16(af, bfr, acc[t], 0, 0, 0);
        }
        __syncthreads();
    }

    const int rl = wv * 16 + (ln >> 4) * 4;
    const int cl = (ln & 15);
    if (MODE == 0) {
#pragma unroll
        for (int t = 0; t < 4; t++) {
            int col = bn * 64 + t * 16 + cl;
            float bv = 0.f;
            if (bias1) bv += bias1[col];
            if (bias2) bv += bias2[col];
#pragma unroll
            for (int r = 0; r < 4; r++)
                outF[(size_t)(bm * 64 + rl + r) * ldC + col] = acc[t][r] + bv;
        }
    } else if (MODE == 1) {
#pragma unroll
        for (int t = 0; t < 4; t++) {
            int col = bn * 64 + t * 16 + cl;
#pragma unroll
            for (int r = 0; r < 4; r++)
                outB[(size_t)(bm * 64 + rl + r) * ldC + col] = f2b(tanhf(acc[t][r]));
        }
    } else {
        float bo[4]; int vg[4];
#pragma unroll
        for (int t = 0; t < 4; t++) {
            int v = vc0 + bn * 64 + t * 16 + cl;
            vg[t] = v;
            bo[t] = (v < NV) ? bias1[v] : 0.f;
        }
#pragma unroll
        for (int r = 0; r < 4; r++) {
            float lg[4]; float m = -1e30f;
#pragma unroll
            for (int t = 0; t < 4; t++) {
                lg[t] = (vg[t] < NV) ? (acc[t][r] + bo[t]) : -1e30f;
                m = fmaxf(m, lg[t]);
            }
            m = fmaxf(m, __shfl_xor(m, 1, 64));
            m = fmaxf(m, __shfl_xor(m, 2, 64));
            m = fmaxf(m, __shfl_xor(m, 4, 64));
            m = fmaxf(m, __shfl_xor(m, 8, 64));
            float s = 0.f;
#pragma unroll
            for (int t = 0; t < 4; t++) s += __expf(lg[t] - m);
            s += __shfl_xor(s, 1, 64); s += __shfl_xor(s, 2, 64);
            s += __shfl_xor(s, 4, 64); s += __shfl_xor(s, 8, 64);
            if (cl == 0) {
                int row = bm * 64 + rl + r;
                int cbg = (vc0 >> 6) + bn;
                pmax[(size_t)cbg * NR + row] = m;
                psum[(size_t)cbg * NR + row] = s;
            }
        }
    }
}

// ---------------- LSTM step: gates = h @ W_hh^T (MFMA), combine with preGI ----------------
__global__ __launch_bounds__(256) void lstm_step(
    const u16* __restrict__ WhhB, const u16* __restrict__ hin,
    u16* __restrict__ hout, const float* __restrict__ preGI_t,
    float* __restrict__ c_state, float* __restrict__ hd_t, u16* __restrict__ hdB_t)
{
    __shared__ float gl[1024]; // [4 gates][16 d][16 b]
    const int tid = threadIdx.x;
    const int g = tid >> 6, ln = tid & 63;
    const int dt = blockIdx.x;
    const int arow = (g * 512 + dt * 16 + (ln & 15)) * 512 + ((ln >> 4) * 8);
    const int brow = (ln & 15) * 512 + ((ln >> 4) * 8);
    f32x4 acc = {0.f, 0.f, 0.f, 0.f};
#pragma unroll
    for (int kb = 0; kb < 512; kb += 32) {
        bf16x8 a = *(const bf16x8*)&WhhB[arow + kb];
        bf16x8 b = *(const bf16x8*)&hin[brow + kb];
        acc = __builtin_amdgcn_mfma_f32_16x16x32_bf16(a, b, acc, 0, 0, 0);
    }
#pragma unroll
    for (int r = 0; r < 4; r++)
        gl[g * 256 + ((ln >> 4) * 4 + r) * 16 + (ln & 15)] = acc[r];
    __syncthreads();
    const int b = tid >> 4, dl = tid & 15;
    const int d = dt * 16 + dl;
    float gi = gl[0 * 256 + dl * 16 + b] + preGI_t[b * 2048 + 0 * 512 + d];
    float gf = gl[1 * 256 + dl * 16 + b] + preGI_t[b * 2048 + 1 * 512 + d];
    float gg = gl[2 * 256 + dl * 16 + b] + preGI_t[b * 2048 + 2 * 512 + d];
    float go = gl[3 * 256 + dl * 16 + b] + preGI_t[b * 2048 + 3 * 512 + d];
    float c = sigm(gf) * c_state[b * 512 + d] + sigm(gi) * tanhf(gg);
    float h = sigm(go) * tanhf(c);
    c_state[b * 512 + d] = c;
    hd_t[b * 512 + d] = h;
    hdB_t[b * 512 + d] = f2b(h);
    hout[b * 512 + d] = f2b(h);
}

// ---------------- encoder attention: scores+softmax+copysum+c_e per (b, t-group of 6) ----------------
__global__ __launch_bounds__(256) void attn_e_k(
    const float* __restrict__ q, const float* __restrict__ h_e,
    const float* __restrict__ algn, float* __restrict__ c_e, float* __restrict__ copysum)
{
    const int b = blockIdx.x, tq = blockIdx.y;
    __shared__ float he[8 * 512];
    __shared__ float sl[TLQ][400];
    __shared__ float part[TLQ * 8 * 33];
    __shared__ float rinv[TLQ];
    const int tid = threadIdx.x;
    const int tl = tid >> 5, ks = tid & 31;

    float2 q2[8];
    if (tl < TLQ) {
        const float* qrow = &q[(size_t)((tq * TLQ + tl) * 16 + b) * 1024];
#pragma unroll
        for (int j = 0; j < 8; j++) q2[j] = *(const float2*)&qrow[ks * 2 + j * 64];
    }

    for (int s0 = 0; s0 < 400; s0 += 8) {
        for (int o = tid * 4; o < 8 * 512; o += 1024) {
            int si = o >> 9, d = o & 511;
            *(float4*)&he[o] = *(const float4*)&h_e[(size_t)((s0 + si) * 16 + b) * 512 + d];
        }
        __syncthreads();
        if (tl < TLQ) {
#pragma unroll
            for (int si = 0; si < 8; si++) {
                const float* hh = &he[si * 512];
                float p = 0.f;
#pragma unroll
                for (int j = 0; j < 8; j++) {
                    float2 h2 = *(const float2*)&hh[ks * 2 + j * 64];
                    p += q2[j].x * h2.x + q2[j].y * h2.y;
                }
                part[(tl * 8 + si) * 33 + ks] = p;
            }
        }
        __syncthreads();
        if (tid < TLQ * 8) {
            int tl2 = tid >> 3, si = tid & 7;
            float v = 0.f;
#pragma unroll
            for (int k2 = 0; k2 < 32; k2++) v += part[(tl2 * 8 + si) * 33 + k2];
            sl[tl2][s0 + si] = v;
        }
        __syncthreads();
    }
    // softmax + copysum
    {
        const int j0 = ks;
        if (tl < TLQ) {
            const int tg = tq * TLQ + tl;
            float m = -1e30f;
            for (int j = j0; j < 400; j += 32) m = fmaxf(m, sl[tl][j]);
#pragma unroll
            for (int mk = 1; mk < 32; mk <<= 1) m = fmaxf(m, __shfl_xor(m, mk, 64));
            float se = 0.f, ca = 0.f;
            for (int j = j0; j < 400; j += 32) {
                float e = __expf(sl[tl][j] - m);
                sl[tl][j] = e;
                se += e;
                ca += e * algn[(size_t)(tg * 16 + b) * 400 + j];
            }
#pragma unroll
            for (int mk = 1; mk < 32; mk <<= 1) { se += __shfl_xor(se, mk, 64); ca += __shfl_xor(ca, mk, 64); }
            if (j0 == 0) { rinv[tl] = 1.f / se; copysum[tg * 16 + b] = ca / se; }
        }
    }
    __syncthreads();
    // c_e
    float acc[TLQ][2];
#pragma unroll
    for (int t2 = 0; t2 < TLQ; t2++) { acc[t2][0] = 0.f; acc[t2][1] = 0.f; }
    const int d0 = tid * 2;
    for (int s0 = 0; s0 < 400; s0 += 8) {
        for (int o = tid * 4; o < 8 * 512; o += 1024) {
            int si = o >> 9, d = o & 511;
            *(float4*)&he[o] = *(const float4*)&h_e[(size_t)((s0 + si) * 16 + b) * 512 + d];
        }
        __syncthreads();
        float2 hv[8];
#pragma unroll
        for (int si = 0; si < 8; si++) hv[si] = *(const float2*)&he[si * 512 + d0];
#pragma unroll
        for (int t2 = 0; t2 < TLQ; t2++) {
            float4 p0 = *(const float4*)&sl[t2][s0];
            float4 p1 = *(const float4*)&sl[t2][s0 + 4];
            acc[t2][0] += p0.x * hv[0].x + p0.y * hv[1].x + p0.z * hv[2].x + p0.w * hv[3].x
                        + p1.x * hv[4].x + p1.y * hv[5].x + p1.z * hv[6].x + p1.w * hv[7].x;
            acc[t2][1] += p0.x * hv[0].y + p0.y * hv[1].y + p0.z * hv[2].y + p0.w * hv[3].y
                        + p1.x * hv[4].y + p1.y * hv[5].y + p1.z * hv[6].y + p1.w * hv[7].y;
        }
        __syncthreads();
    }
#pragma unroll
    for (int t2 = 0; t2 < TLQ; t2++) {
        int tg = tq * TLQ + t2;
        float inv = rinv[t2];
        float2 o2; o2.x = acc[t2][0] * inv; o2.y = acc[t2][1] * inv;
        *(float2*)&c_e[(size_t)(tg * 16 + b) * 512 + d0] = o2;
    }
}

// ---------------- decoder self-attention (causal): per (b, t-group of 6) ----------------
__global__ __launch_bounds__(256) void attn_d_k(
    const float* __restrict__ q, const float* __restrict__ hd, float* __restrict__ c_d)
{
    const int b = blockIdx.x, tq = blockIdx.y;
    __shared__ float ul[8 * 512];
    __shared__ float sl[TLQ][64];
    __shared__ float part[TLQ * 8 * 33];
    __shared__ float rinv[TLQ];
    const int tid = threadIdx.x;
    const int tl = tid >> 5, ks = tid & 31;

    float2 q2[8];
    if (tl < TLQ) {
        const float* qrow = &q[(size_t)((tq * TLQ + tl) * 16 + b) * 1024 + 512];
#pragma unroll
        for (int j = 0; j < 8; j++) q2[j] = *(const float2*)&qrow[ks * 2 + j * 64];
    }

    for (int u0 = 0; u0 < 64; u0 += 8) {
        for (int o = tid * 4; o < 8 * 512; o += 1024) {
            int ui = o >> 9, d = o & 511;
            int u = u0 + ui;
            float4 v4 = make_float4(0.f, 0.f, 0.f, 0.f);
            if (u < 60) v4 = *(const float4*)&hd[(size_t)(u * 16 + b) * 512 + d];
            *(float4*)&ul[o] = v4;
        }
        __syncthreads();
        if (tl < TLQ) {
#pragma unroll
            for (int ui = 0; ui < 8; ui++) {
                const float* hh = &ul[ui * 512];
                float p = 0.f;
#pragma unroll
                for (int j = 0; j < 8; j++) {
                    float2 h2 = *(const float2*)&hh[ks * 2 + j * 64];
                    p += q2[j].x * h2.x + q2[j].y * h2.y;
                }
                part[(tl * 8 + ui) * 33 + ks] = p;
            }
        }
        __syncthreads();
        if (tid < TLQ * 8) {
            int tl2 = tid >> 3, ui = tid & 7;
            int u = u0 + ui, tg = tq * TLQ + tl2;
            float v = 0.f;
#pragma unroll
            for (int k2 = 0; k2 < 32; k2++) v += part[(tl2 * 8 + ui) * 33 + k2];
            sl[tl2][u] = (u <= tg && u < 60) ? v : -1e30f;
        }
        __syncthreads();
    }
    {
        const int j0 = ks;
        if (tl < TLQ) {
            float m = -1e30f;
            for (int j = j0; j < 60; j += 32) m = fmaxf(m, sl[tl][j]);
#pragma unroll
            for (int mk = 1; mk < 32; mk <<= 1) m = fmaxf(m, __shfl_xor(m, mk, 64));
            float se = 0.f;
            for (int j = j0; j < 60; j += 32) { float e = __expf(sl[tl][j] - m); sl[tl][j] = e; se += e; }
#pragma unroll
            for (int mk = 1; mk < 32; mk <<= 1) se += __shfl_xor(se, mk, 64);
            if (j0 == 0) rinv[tl] = 1.f / se;
            if (j0 < 4) sl[tl][60 + j0] = 0.f;
        }
    }
    __syncthreads();
    float acc[TLQ][2];
#pragma unroll
    for (int t2 = 0; t2 < TLQ; t2++) { acc[t2][0] = 0.f; acc[t2][1] = 0.f; }
    const int d0 = tid * 2;
    for (int u0 = 0; u0 < 64; u0 += 8) {
        for (int o = tid * 4; o < 8 * 512; o += 1024) {
            int ui = o >> 9, d = o & 511;
            int u = u0 + ui;
            float4 v4 = make_float4(0.f, 0.f, 0.f, 0.f);
            if (u < 60) v4 = *(const float4*)&hd[(size_t)(u * 16 + b) * 512 + d];
            *(float4*)&ul[o] = v4;
        }
        __syncthreads();
        float2 hv[8];
#pragma unroll
        for (int ui = 0; ui < 8; ui++) hv[ui] = *(const float2*)&ul[ui * 512 + d0];
#pragma unroll
        for (int t2 = 0; t2 < TLQ; t2++) {
            float4 p0 = *(const float4*)&sl[t2][u0];
            float4 p1 = *(const float4*)&sl[t2][u0 + 4];
            acc[t2][0] += p0.x * hv[0].x + p0.y * hv[1].x + p0.z * hv[2].x + p0.w * hv[3].x
                        + p1.x * hv[4].x + p1.y * hv[5].x + p1.z * hv[6].x + p1.w * hv[7].x;
            acc[t2][1] += p0.x * hv[0].y + p0.y * hv[1].y + p0.z * hv[2].y + p0.w * hv[3].y
                        + p1.x * hv[4].y + p1.y * hv[5].y + p1.z * hv[6].y + p1.w * hv[7].y;
        }
        __syncthreads();
    }
#pragma unroll
    for (int t2 = 0; t2 < TLQ; t2++) {
        int tg = tq * TLQ + t2;
        float sc = (tg == 0) ? 0.f : rinv[t2];
        float2 o2; o2.x = acc[t2][0] * sc; o2.y = acc[t2][1] * sc;
        *(float2*)&c_d[(size_t)(tg * 16 + b) * 512 + d0] = o2;
    }
}

// ---------------- cat assembly + p_switch ----------------
__global__ __launch_bounds__(256) void cat_k(
    const float* __restrict__ hd, const float* __restrict__ c_e, const float* __restrict__ c_d,
    const float* __restrict__ W_u, const float* __restrict__ b_u,
    u16* __restrict__ catB, float* __restrict__ p_switch)
{
    const int r = blockIdx.x, tid = threadIdx.x;
    float partial = 0.f;
    for (int j = tid; j < 1536; j += 256) {
        float v;
        if (j < 512) v = hd[(size_t)r * 512 + j];
        else if (j < 1024) v = c_e[(size_t)r * 512 + (j - 512)];
        else v = c_d[(size_t)r * 512 + (j - 1024)];
        catB[(size_t)r * 1536 + j] = f2b(v);
        partial += v * W_u[j];
    }
#pragma unroll
    for (int mk = 1; mk < 64; mk <<= 1) partial += __shfl_xor(partial, mk, 64);
    __shared__ float red[4];
    if ((tid & 63) == 0) red[tid >> 6] = partial;
    __syncthreads();
    if (tid == 0) {
        float u = red[0] + red[1] + red[2] + red[3] + b_u[0];
        p_switch[r] = 1.f / (1.f + __expf(-u));
    }
}

// ---------------- targ logit (recompute W_out row on the fly) ----------------
__global__ __launch_bounds__(256) void targ_k(
    const int* __restrict__ tgt, const u16* __restrict__ WembB,
    const u16* __restrict__ WprojT, const u16* __restrict__ catB,
    const float* __restrict__ b_out, float* __restrict__ lt)
{
    const int r = blockIdx.x, tid = threadIdx.x;
    const int v = tgt[r];
    float partial = 0.f;
    for (int k = tid; k < 1536; k += 256) {
        float wk = 0.f;
        const u16* ae = &WembB[(size_t)v * 128];
        const u16* be = &WprojT[(size_t)k * 128];
#pragma unroll 4
        for (int e = 0; e < 128; e++) wk += b2f(ae[e]) * b2f(be[e]);
        float w = b2f(f2b(tanhf(wk)));
        partial += w * b2f(catB[(size_t)r * 1536 + k]);
    }
#pragma unroll
    for (int mk = 1; mk < 64; mk <<= 1) partial += __shfl_xor(partial, mk, 64);
    __shared__ float red[4];
    if ((tid & 63) == 0) red[tid >> 6] = partial;
    __syncthreads();
    if (tid == 0) lt[r] = red[0] + red[1] + red[2] + red[3] + b_out[v];
}

// ---------------- per-row LSE combine + loss term ----------------
__global__ __launch_bounds__(256) void rowred_k(
    const float* __restrict__ pmax, const float* __restrict__ psum,
    const float* __restrict__ lt, const float* __restrict__ p_switch,
    const float* __restrict__ copysum, const int* __restrict__ tgt,
    float* __restrict__ terms)
{
    const int r = blockIdx.x * 256 + threadIdx.x;
    if (r >= NR) return;
    float M = -1e30f;
    for (int cb = 0; cb < NCB; cb++) M = fmaxf(M, pmax[(size_t)cb * NR + r]);
    float S = 0.f;
    for (int cb = 0; cb < NCB; cb++) S += psum[(size_t)cb * NR + r] * __expf(pmax[(size_t)cb * NR + r] - M);
    float ps = p_switch[r];
    float tg = (1.f - ps) * __expf(lt[r] - M) / S;
    float tc = ps * copysum[r];
    terms[r] = (tgt[r] != 0) ? -logf(tg + tc + 2e-12f) : 0.f;
}

__global__ __launch_bounds__(256) void final_k(const float* __restrict__ terms, float* __restrict__ out)
{
    const int tid = threadIdx.x;
    float p = 0.f;
    for (int i = tid; i < NR; i += 256) p += terms[i];
#pragma unroll
    for (int mk = 1; mk < 64; mk <<= 1) p += __shfl_xor(p, mk, 64);
    __shared__ float red[4];
    if ((tid & 63) == 0) red[tid >> 6] = p;
    __syncthreads();
    if (tid == 0) out[0] = red[0] + red[1] + red[2] + red[3];
}

// ---------------- host launch ----------------
extern "C" void kernel_launch(void* const* d_in, const int* in_sizes, int n_in,
                              void* d_out, int out_size, void* d_ws, size_t ws_size,
                              hipStream_t stream)
{
    const int*   tgt    = (const int*)d_in[0];
    const float* algn   = (const float*)d_in[2];
    const float* h_e    = (const float*)d_in[3];
    const float* h0     = (const float*)d_in[4];
    const float* c0     = (const float*)d_in[5];
    const float* W_emb  = (const float*)d_in[6];
    const float* W_ih   = (const float*)d_in[7];
    const float* W_hh   = (const float*)d_in[8];
    const float* b_ih   = (const float*)d_in[9];
    const float* b_hh   = (const float*)d_in[10];
    const float* W_ae   = (const float*)d_in[11];
    const float* W_ad   = (const float*)d_in[12];
    const float* W_proj = (const float*)d_in[13];
    const float* W_u    = (const float*)d_in[14];
    const float* b_u    = (const float*)d_in[15];
    const float* b_out  = (const float*)d_in[16];
    (void)in_sizes; (void)n_in; (void)out_size; (void)ws_size;

    char* ws = (char*)d_ws;
    size_t off = 0;
    auto alloc = [&](size_t bytes) -> char* {
        char* p = ws + off;
        off += (bytes + 255) & ~(size_t)255;
        return p;
    };
    u16* wbuf    = (u16*)alloc((size_t)12800 * 1536 * 2);
    u16* catB    = (u16*)alloc((size_t)NR * 1536 * 2);
    u16* WprojT  = (u16*)alloc((size_t)1536 * 128 * 2);
    u16* WihB    = (u16*)alloc((size_t)2048 * 128 * 2);
    u16* WhhB    = (u16*)alloc((size_t)2048 * 512 * 2);
    u16* WattnT  = (u16*)alloc((size_t)1024 * 512 * 2);
    u16* WembB   = (u16*)alloc((size_t)NVP * 128 * 2);
    u16* embB    = (u16*)alloc((size_t)NR * 128 * 2);
    u16* hdB     = (u16*)alloc((size_t)NR * 512 * 2);
    u16* hB      = (u16*)alloc((size_t)2 * 8192 * 2);
    float* preGI = (float*)alloc((size_t)NR * 2048 * 4);
    float* hd    = (float*)alloc((size_t)NR * 512 * 4);
    float* c_st  = (float*)alloc((size_t)8192 * 4);
    float* q     = (float*)alloc((size_t)NR * 1024 * 4);
    float* c_e   = (float*)alloc((size_t)NR * 512 * 4);
    float* c_d   = (float*)alloc((size_t)NR * 512 * 4);
    float* p_sw  = (float*)alloc(NR * 4);
    float* copys = (float*)alloc(NR * 4);
    float* lt    = (float*)alloc(NR * 4);
    float* terms = (float*)alloc(NR * 4);
    float* pmax  = (float*)alloc((size_t)NCB * NR * 4);
    float* psum  = (float*)alloc((size_t)NCB * NR * 4);

    // prep
    conv_k<<<dim3((2048 * 128 + 255) / 256), 256, 0, stream>>>(W_ih, WihB, 2048 * 128);
    conv_k<<<dim3((2048 * 512 + 255) / 256), 256, 0, stream>>>(W_hh, WhhB, 2048 * 512);
    embpad_k<<<dim3((NVP * 128 + 255) / 256), 256, 0, stream>>>(W_emb, WembB);
    attnT_k<<<dim3((1024 * 512 + 255) / 256), 256, 0, stream>>>(W_ae, W_ad, WattnT);
    projT_k<<<dim3((1536 * 128 + 255) / 256), 256, 0, stream>>>(W_proj, WprojT);
    gather_k<<<dim3((NR * 128 + 255) / 256), 256, 0, stream>>>(W_emb, tgt, embB);
    init_k<<<dim3(32), 256, 0, stream>>>(c0, h0, c_st, hB);

    // preGI = emb @ W_ih^T + b_ih + b_hh
    gemm_k<0><<<dim3(2048 / 64, NR / 64), 256, 0, stream>>>(
        embB, WihB, 128, 2048, preGI, nullptr, b_ih, b_hh, nullptr, nullptr, 0);

    // LSTM, 60 sequential steps
    for (int t = 0; t < 60; t++) {
        const u16* hin = hB + (size_t)(t & 1) * 8192;
        u16* hout = hB + (size_t)((t & 1) ^ 1) * 8192;
        lstm_step<<<dim3(32), 256, 0, stream>>>(
            WhhB, hin, hout, preGI + (size_t)t * 16 * 2048,
            c_st, hd + (size_t)t * 8192, hdB + (size_t)t * 8192);
    }

    // q = hd @ [W_attn_e | W_attn_d]
    gemm_k<0><<<dim3(1024 / 64, NR / 64), 256, 0, stream>>>(
        hdB, WattnT, 512, 1024, q, nullptr, nullptr, nullptr, nullptr, nullptr, 0);

    attn_e_k<<<dim3(16, 10), 256, 0, stream>>>(q, h_e, algn, c_e, copys);
    attn_d_k<<<dim3(16, 10), 256, 0, stream>>>(q, hd, c_d);
    cat_k<<<dim3(NR), 256, 0, stream>>>(hd, c_e, c_d, W_u, b_u, catB, p_sw);

    // chunked: W_out chunk = tanh(W_emb @ W_proj), then cat @ chunk^T with streaming LSE
    const int vc0s[4] = {0, 12800, 25600, 38400};
    const int nccs[4] = {12800, 12800, 12800, 11904};
    for (int c = 0; c < 4; c++) {
        gemm_k<1><<<dim3(1536 / 64, nccs[c] / 64), 256, 0, stream>>>(
            WembB + (size_t)vc0s[c] * 128, WprojT, 128, 1536,
            nullptr, wbuf, nullptr, nullptr, nullptr, nullptr, 0);
        gemm_k<2><<<dim3(nccs[c] / 64, NR / 64), 256, 0, stream>>>(
            catB, wbuf, 1536, 0, nullptr, nullptr, b_out, nullptr, pmax, psum, vc0s[c]);
    }

    targ_k<<<dim3(NR), 256, 0, stream>>>(tgt, WembB, WprojT, catB, b_out, lt);
    rowred_k<<<dim3(4), 256, 0, stream>>>(pmax, psum, lt, p_sw, copys, tgt, terms);
    final_k<<<dim3(1), 256, 0, stream>>>(terms, (float*)d_out);
}

// Round 2
// 1026.785 us; speedup vs baseline: 1.3208x; 1.3208x over previous
//
#include <hip/hip_runtime.h>

typedef unsigned short u16;
typedef __attribute__((ext_vector_type(8))) short bf16x8;
typedef __attribute__((ext_vector_type(4))) float f32x4;

#define NV 50257
#define NVP 50304
#define NR 960          // 60*16 rows
#define NCB 786         // 50304/64 col blocks

__device__ __forceinline__ u16 f2b(float x) {
    union { float f; unsigned u; } v; v.f = x;
    unsigned r = v.u + 0x7FFFu + ((v.u >> 16) & 1u);
    return (u16)(r >> 16);
}
__device__ __forceinline__ float b2f(u16 h) {
    union { unsigned u; float f; } v; v.u = ((unsigned)h) << 16;
    return v.f;
}
__device__ __forceinline__ float sigm(float x) { return 1.f / (1.f + __expf(-x)); }

__device__ __forceinline__ void gload16(const u16* g, u16* l) {
    __builtin_amdgcn_global_load_lds((const __attribute__((address_space(1))) void*)g,
                                     (__attribute__((address_space(3))) void*)l, 16, 0, 0);
}

// ---------------- prep kernels ----------------
__global__ void conv_k(const float* __restrict__ in, u16* __restrict__ out, int n) {
    int i = blockIdx.x * 256 + threadIdx.x;
    if (i < n) out[i] = f2b(in[i]);
}
__global__ void embpad_k(const float* __restrict__ W_emb, u16* __restrict__ out) {
    int i = blockIdx.x * 256 + threadIdx.x;
    if (i < NVP * 128) out[i] = (i < NV * 128) ? f2b(W_emb[i]) : (u16)0;
}
__global__ void attnT_k(const float* __restrict__ We, const float* __restrict__ Wd, u16* __restrict__ out) {
    int i = blockIdx.x * 256 + threadIdx.x;
    if (i < 1024 * 512) {
        int n = i >> 9, k = i & 511;
        float v = (n < 512) ? We[k * 512 + n] : Wd[k * 512 + (n - 512)];
        out[i] = f2b(v);
    }
}
__global__ void projT_k(const float* __restrict__ Wp, u16* __restrict__ out) {
    int i = blockIdx.x * 256 + threadIdx.x;
    if (i < 1536 * 128) {
        int k = i >> 7, e = i & 127;
        out[i] = f2b(Wp[e * 1536 + k]);
    }
}
__global__ void gather_k(const float* __restrict__ W_emb, const int* __restrict__ tgt, u16* __restrict__ out) {
    int i = blockIdx.x * 256 + threadIdx.x;
    if (i < NR * 128) {
        int r = i >> 7, e = i & 127;
        out[i] = f2b(W_emb[(size_t)tgt[r] * 128 + e]);
    }
}
__global__ void init_k(const float* __restrict__ c0, const float* __restrict__ h0,
                       float* __restrict__ c_state, u16* __restrict__ hb0) {
    int i = blockIdx.x * 256 + threadIdx.x;
    if (i < 8192) { c_state[i] = c0[i]; hb0[i] = f2b(h0[i]); }
}

// h_e [s][b][512] f32 -> h_eB [b][448][512] bf16 (pad s zero), h_eT [b][512][448] bf16
__global__ __launch_bounds__(256) void prep_he_k(const float* __restrict__ h_e,
                                                 u16* __restrict__ h_eB, u16* __restrict__ h_eT) {
    __shared__ u16 tile[64][68];
    const int st = blockIdx.x, b = blockIdx.y, tid = threadIdx.x;
    for (int dc = 0; dc < 8; dc++) {
        const int d0 = dc * 64;
#pragma unroll
        for (int k = 0; k < 4; k++) {
            int o = k * 256 + tid;
            int si = o >> 4, d4 = (o & 15) * 4;
            int s = st * 64 + si;
            float4 f = make_float4(0.f, 0.f, 0.f, 0.f);
            if (s < 400) f = *(const float4*)&h_e[((size_t)s * 16 + b) * 512 + d0 + d4];
            tile[si][d4 + 0] = f2b(f.x); tile[si][d4 + 1] = f2b(f.y);
            tile[si][d4 + 2] = f2b(f.z); tile[si][d4 + 3] = f2b(f.w);
        }
        __syncthreads();
#pragma unroll
        for (int k = 0; k < 4; k++) {
            int o = k * 256 + tid;
            int si = o >> 4, d4 = (o & 15) * 4;
            ushort4 u; u.x = tile[si][d4]; u.y = tile[si][d4 + 1]; u.z = tile[si][d4 + 2]; u.w = tile[si][d4 + 3];
            *(ushort4*)&h_eB[((size_t)b * 448 + st * 64 + si) * 512 + d0 + d4] = u;
        }
#pragma unroll
        for (int k = 0; k < 4; k++) {
            int o = k * 256 + tid;
            int di = o >> 4, s4 = (o & 15) * 4;
            ushort4 u; u.x = tile[s4][di]; u.y = tile[s4 + 1][di]; u.z = tile[s4 + 2][di]; u.w = tile[s4 + 3][di];
            *(ushort4*)&h_eT[((size_t)b * 512 + d0 + di) * 448 + st * 64 + s4] = u;
        }
        __syncthreads();
    }
}

// hd [(u*16+b)][512] f32 -> hdUB [b][64][512] bf16 (pad u zero), hdT [b][512][64] bf16
__global__ __launch_bounds__(256) void prep_hd_k(const float* __restrict__ hd,
                                                 u16* __restrict__ hdUB, u16* __restrict__ hdT) {
    __shared__ u16 tile[64][68];
    const int b = blockIdx.x, tid = threadIdx.x;
    for (int dc = 0; dc < 8; dc++) {
        const int d0 = dc * 64;
#pragma unroll
        for (int k = 0; k < 4; k++) {
            int o = k * 256 + tid;
            int ui = o >> 4, d4 = (o & 15) * 4;
            float4 f = make_float4(0.f, 0.f, 0.f, 0.f);
            if (ui < 60) f = *(const float4*)&hd[((size_t)ui * 16 + b) * 512 + d0 + d4];
            tile[ui][d4 + 0] = f2b(f.x); tile[ui][d4 + 1] = f2b(f.y);
            tile[ui][d4 + 2] = f2b(f.z); tile[ui][d4 + 3] = f2b(f.w);
        }
        __syncthreads();
#pragma unroll
        for (int k = 0; k < 4; k++) {
            int o = k * 256 + tid;
            int ui = o >> 4, d4 = (o & 15) * 4;
            ushort4 u; u.x = tile[ui][d4]; u.y = tile[ui][d4 + 1]; u.z = tile[ui][d4 + 2]; u.w = tile[ui][d4 + 3];
            *(ushort4*)&hdUB[((size_t)b * 64 + ui) * 512 + d0 + d4] = u;
        }
#pragma unroll
        for (int k = 0; k < 4; k++) {
            int o = k * 256 + tid;
            int di = o >> 4, u4 = (o & 15) * 4;
            ushort4 u; u.x = tile[u4][di]; u.y = tile[u4 + 1][di]; u.z = tile[u4 + 2][di]; u.w = tile[u4 + 3][di];
            *(ushort4*)&hdT[((size_t)b * 512 + d0 + di) * 64 + u4] = u;
        }
        __syncthreads();
    }
}

// q [(t*16+b)][1024] f32 -> qeB [b][64][512], qdB [b][64][512] bf16 (pad t zero)
__global__ void qprep_k(const float* __restrict__ q, u16* __restrict__ qeB, u16* __restrict__ qdB) {
    const int t = blockIdx.x, b = blockIdx.y, tid = threadIdx.x;
    const int o = tid * 4;
    float4 f = make_float4(0.f, 0.f, 0.f, 0.f);
    if (t < 60) f = *(const float4*)&q[((size_t)t * 16 + b) * 1024 + o];
    ushort4 u; u.x = f2b(f.x); u.y = f2b(f.y); u.z = f2b(f.z); u.w = f2b(f.w);
    if (o < 512) *(ushort4*)&qeB[((size_t)b * 64 + t) * 512 + o] = u;
    else         *(ushort4*)&qdB[((size_t)b * 64 + t) * 512 + (o - 512)] = u;
}

// ---------------- 64x64 bf16 MFMA GEMM, f32 out (small mats) ----------------
__global__ __launch_bounds__(256) void gemm64_k(
    const u16* __restrict__ A, const u16* __restrict__ Bm,
    int K, int ldC, float* __restrict__ outF,
    const float* __restrict__ bias1, const float* __restrict__ bias2)
{
    __shared__ u16 Al[64 * 40];
    __shared__ u16 Bl[64 * 40];
    const int tid = threadIdx.x;
    const int wv = tid >> 6, ln = tid & 63;
    const int bn = blockIdx.x, bm = blockIdx.y;
    const int srow = tid >> 2;
    const int skc = (tid & 3) * 8;
    const size_t aoff = (size_t)(bm * 64 + srow) * K + skc;
    const size_t boff = (size_t)(bn * 64 + srow) * K + skc;
    f32x4 acc[4];
#pragma unroll
    for (int t = 0; t < 4; t++) acc[t] = (f32x4){0.f, 0.f, 0.f, 0.f};
    const int fra = (wv * 16 + (ln & 15)) * 40 + (ln >> 4) * 8;
    for (int kb = 0; kb < K; kb += 32) {
        *(bf16x8*)&Al[srow * 40 + skc] = *(const bf16x8*)&A[aoff + kb];
        *(bf16x8*)&Bl[srow * 40 + skc] = *(const bf16x8*)&Bm[boff + kb];
        __syncthreads();
        bf16x8 af = *(const bf16x8*)&Al[fra];
#pragma unroll
        for (int t = 0; t < 4; t++) {
            bf16x8 bfr = *(const bf16x8*)&Bl[(t * 16 + (ln & 15)) * 40 + (ln >> 4) * 8];
            acc[t] = __builtin_amdgcn_mfma_f32_16x16x32_bf16(af, bfr, acc[t], 0, 0, 0);
        }
        __syncthreads();
    }
    const int rl = wv * 16 + (ln >> 4) * 4;
    const int cl = (ln & 15);
#pragma unroll
    for (int t = 0; t < 4; t++) {
        int col = bn * 64 + t * 16 + cl;
        float bv = 0.f;
        if (bias1) bv += bias1[col];
        if (bias2) bv += bias2[col];
#pragma unroll
        for (int r = 0; r < 4; r++)
            outF[(size_t)(bm * 64 + rl + r) * ldC + col] = acc[t][r] + bv;
    }
}

// ---------------- batched 64-wide A*B^T GEMM (M=64), f32 out ----------------
__global__ __launch_bounds__(256) void gemm_b_k(
    const u16* __restrict__ A, long sA,
    const u16* __restrict__ Bm, long sB, int K,
    float* __restrict__ C, long sC, int ldC)
{
    __shared__ u16 Al[64 * 40];
    __shared__ u16 Bl[64 * 40];
    const int tid = threadIdx.x;
    const int wv = tid >> 6, ln = tid & 63;
    const int bn = blockIdx.x, bz = blockIdx.z;
    A += (size_t)bz * sA; Bm += (size_t)bz * sB; C += (size_t)bz * sC;
    const int srow = tid >> 2;
    const int skc = (tid & 3) * 8;
    const size_t aoff = (size_t)srow * K + skc;
    const size_t boff = (size_t)(bn * 64 + srow) * K + skc;
    f32x4 acc[4];
#pragma unroll
    for (int t = 0; t < 4; t++) acc[t] = (f32x4){0.f, 0.f, 0.f, 0.f};
    const int fra = (wv * 16 + (ln & 15)) * 40 + (ln >> 4) * 8;
    for (int kb = 0; kb < K; kb += 32) {
        *(bf16x8*)&Al[srow * 40 + skc] = *(const bf16x8*)&A[aoff + kb];
        *(bf16x8*)&Bl[srow * 40 + skc] = *(const bf16x8*)&Bm[boff + kb];
        __syncthreads();
        bf16x8 af = *(const bf16x8*)&Al[fra];
#pragma unroll
        for (int t = 0; t < 4; t++) {
            bf16x8 bfr = *(const bf16x8*)&Bl[(t * 16 + (ln & 15)) * 40 + (ln >> 4) * 8];
            acc[t] = __builtin_amdgcn_mfma_f32_16x16x32_bf16(af, bfr, acc[t], 0, 0, 0);
        }
        __syncthreads();
    }
    const int rl = wv * 16 + (ln >> 4) * 4;
    const int cl = (ln & 15);
#pragma unroll
    for (int t = 0; t < 4; t++) {
        int col = bn * 64 + t * 16 + cl;
#pragma unroll
        for (int r = 0; r < 4; r++)
            C[(size_t)(rl + r) * ldC + col] = acc[t][r];
    }
}

// ---------------- 128x128 m97-style GEMM: MODE1 tanh->bf16, MODE2 streaming LSE ----------------
template<int MODE>
__global__ __launch_bounds__(256) void gemm128_k(
    const u16* __restrict__ A, const u16* __restrict__ Bm, const int K,
    u16* __restrict__ outB, const int ldO,
    const float* __restrict__ bias,
    float* __restrict__ pmax, float* __restrict__ psum, const int vc0)
{
    __shared__ u16 Al[128 * 32];
    __shared__ u16 Bl[128 * 32];
    const int tid = threadIdx.x;
    const int w = tid >> 6, ln = tid & 63;
    const int wr = w >> 1, wc = w & 1;
    const int bn = blockIdx.x, bm = blockIdx.y;
    const int srow = w * 16 + (ln >> 2);
    const int scol = (ln & 3) * 8;
    const u16* ag = A + (size_t)bm * 128 * K + (size_t)srow * K + scol;
    const u16* bg = Bm + (size_t)bn * 128 * K + (size_t)srow * K + scol;
    u16* la = &Al[w * 16 * 32];
    u16* lb = &Bl[w * 16 * 32];
    f32x4 acc[4][4];
#pragma unroll
    for (int m = 0; m < 4; m++)
#pragma unroll
        for (int n = 0; n < 4; n++) acc[m][n] = (f32x4){0.f, 0.f, 0.f, 0.f};
    const int ra = (wr * 64 + (ln & 15)) * 32 + (ln >> 4) * 8;
    const int rb = (wc * 64 + (ln & 15)) * 32 + (ln >> 4) * 8;

    for (int kb = 0; kb < K; kb += 32) {
        gload16(ag + kb, la);
        gload16(ag + (size_t)64 * K + kb, la + 64 * 32);
        gload16(bg + kb, lb);
        gload16(bg + (size_t)64 * K + kb, lb + 64 * 32);
        __syncthreads();
        bf16x8 af[4], bfr[4];
#pragma unroll
        for (int m = 0; m < 4; m++) af[m] = *(const bf16x8*)&Al[ra + m * 16 * 32];
#pragma unroll
        for (int n = 0; n < 4; n++) bfr[n] = *(const bf16x8*)&Bl[rb + n * 16 * 32];
#pragma unroll
        for (int m = 0; m < 4; m++)
#pragma unroll
            for (int n = 0; n < 4; n++)
                acc[m][n] = __builtin_amdgcn_mfma_f32_16x16x32_bf16(af[m], bfr[n], acc[m][n], 0, 0, 0);
        __syncthreads();
    }

    const int cl = ln & 15, rg = ln >> 4;
    if (MODE == 1) {
#pragma unroll
        for (int m = 0; m < 4; m++) {
            int row0 = bm * 128 + wr * 64 + m * 16 + rg * 4;
#pragma unroll
            for (int n = 0; n < 4; n++) {
                int col = bn * 128 + wc * 64 + n * 16 + cl;
#pragma unroll
                for (int r = 0; r < 4; r++)
                    outB[(size_t)(row0 + r) * ldO + col] = f2b(tanhf(acc[m][n][r]));
            }
        }
    } else {
        const int cbg = (vc0 >> 6) + bn * 2 + wc;
        float bo[4]; int vg[4];
#pragma unroll
        for (int n = 0; n < 4; n++) {
            vg[n] = vc0 + bn * 128 + wc * 64 + n * 16 + cl;
            bo[n] = (vg[n] < NV) ? bias[vg[n]] : 0.f;
        }
#pragma unroll
        for (int m = 0; m < 4; m++) {
            int row0 = bm * 128 + wr * 64 + m * 16 + rg * 4;
#pragma unroll
            for (int r = 0; r < 4; r++) {
                float lg[4]; float mm = -1e30f;
#pragma unroll
                for (int n = 0; n < 4; n++) {
                    lg[n] = (vg[n] < NV) ? (acc[m][n][r] + bo[n]) : -1e30f;
                    mm = fmaxf(mm, lg[n]);
                }
                mm = fmaxf(mm, __shfl_xor(mm, 1, 64));
                mm = fmaxf(mm, __shfl_xor(mm, 2, 64));
                mm = fmaxf(mm, __shfl_xor(mm, 4, 64));
                mm = fmaxf(mm, __shfl_xor(mm, 8, 64));
                float s = 0.f;
#pragma unroll
                for (int n = 0; n < 4; n++) s += __expf(lg[n] - mm);
                s += __shfl_xor(s, 1, 64); s += __shfl_xor(s, 2, 64);
                s += __shfl_xor(s, 4, 64); s += __shfl_xor(s, 8, 64);
                int row = row0 + r;
                if (cl == 0 && row < NR) {
                    pmax[(size_t)cbg * NR + row] = mm;
                    psum[(size_t)cbg * NR + row] = s;
                }
            }
        }
    }
}

// ---------------- LSTM step ----------------
__global__ __launch_bounds__(256) void lstm_step(
    const u16* __restrict__ WhhB, const u16* __restrict__ hin,
    u16* __restrict__ hout, const float* __restrict__ preGI_t,
    float* __restrict__ c_state, float* __restrict__ hd_t, u16* __restrict__ hdB_t)
{
    __shared__ float gl[1024];
    const int tid = threadIdx.x;
    const int g = tid >> 6, ln = tid & 63;
    const int dt = blockIdx.x;
    const int arow = (g * 512 + dt * 16 + (ln & 15)) * 512 + ((ln >> 4) * 8);
    const int brow = (ln & 15) * 512 + ((ln >> 4) * 8);
    f32x4 acc = {0.f, 0.f, 0.f, 0.f};
#pragma unroll
    for (int kb = 0; kb < 512; kb += 32) {
        bf16x8 a = *(const bf16x8*)&WhhB[arow + kb];
        bf16x8 b = *(const bf16x8*)&hin[brow + kb];
        acc = __builtin_amdgcn_mfma_f32_16x16x32_bf16(a, b, acc, 0, 0, 0);
    }
#pragma unroll
    for (int r = 0; r < 4; r++)
        gl[g * 256 + ((ln >> 4) * 4 + r) * 16 + (ln & 15)] = acc[r];
    __syncthreads();
    const int b = tid >> 4, dl = tid & 15;
    const int d = dt * 16 + dl;
    float gi = gl[0 * 256 + dl * 16 + b] + preGI_t[b * 2048 + 0 * 512 + d];
    float gf = gl[1 * 256 + dl * 16 + b] + preGI_t[b * 2048 + 1 * 512 + d];
    float gg = gl[2 * 256 + dl * 16 + b] + preGI_t[b * 2048 + 2 * 512 + d];
    float go = gl[3 * 256 + dl * 16 + b] + preGI_t[b * 2048 + 3 * 512 + d];
    float c = sigm(gf) * c_state[b * 512 + d] + sigm(gi) * tanhf(gg);
    float h = sigm(go) * tanhf(c);
    c_state[b * 512 + d] = c;
    hd_t[b * 512 + d] = h;
    hdB_t[b * 512 + d] = f2b(h);
    hout[b * 512 + d] = f2b(h);
}

// ---------------- softmax kernels ----------------
__global__ __launch_bounds__(256) void softmax_e_k(
    const float* __restrict__ Se, const float* __restrict__ algn,
    u16* __restrict__ PeB, float* __restrict__ copysum)
{
    const int wid = blockIdx.x * 4 + (threadIdx.x >> 6);
    const int l = threadIdx.x & 63;
    const int t = wid >> 4, b = wid & 15;
    const float* srow = &Se[((size_t)b * 64 + t) * 448];
    float v[7];
    float m = -1e30f;
#pragma unroll
    for (int i = 0; i < 7; i++) {
        int s = l + i * 64;
        v[i] = (s < 400) ? srow[s] : -1e30f;
        m = fmaxf(m, v[i]);
    }
#pragma unroll
    for (int mk = 1; mk < 64; mk <<= 1) m = fmaxf(m, __shfl_xor(m, mk, 64));
    const float* arow = &algn[((size_t)t * 16 + b) * 400];
    float se = 0.f, ca = 0.f;
#pragma unroll
    for (int i = 0; i < 7; i++) {
        int s = l + i * 64;
        float e = (s < 400) ? __expf(v[i] - m) : 0.f;
        v[i] = e; se += e;
        if (s < 400) ca += e * arow[s];
    }
#pragma unroll
    for (int mk = 1; mk < 64; mk <<= 1) { se += __shfl_xor(se, mk, 64); ca += __shfl_xor(ca, mk, 64); }
    float inv = 1.f / se;
#pragma unroll
    for (int i = 0; i < 7; i++) {
        int s = l + i * 64;
        PeB[((size_t)b * 64 + t) * 448 + s] = f2b(v[i] * inv);
    }
    if (l == 0) copysum[t * 16 + b] = ca * inv;
}

__global__ __launch_bounds__(256) void softmax_d_k(const float* __restrict__ Sd, u16* __restrict__ PdB)
{
    const int wid = blockIdx.x * 4 + (threadIdx.x >> 6);
    const int l = threadIdx.x & 63;
    const int t = wid >> 4, b = wid & 15;
    float v = Sd[((size_t)b * 64 + t) * 64 + l];
    bool ok = (l <= t) && (l < 60);
    v = ok ? v : -1e30f;
    float m = v;
#pragma unroll
    for (int mk = 1; mk < 64; mk <<= 1) m = fmaxf(m, __shfl_xor(m, mk, 64));
    float e = ok ? __expf(v - m) : 0.f;
    float se = e;
#pragma unroll
    for (int mk = 1; mk < 64; mk <<= 1) se += __shfl_xor(se, mk, 64);
    float p = (t == 0) ? 0.f : e / se;
    PdB[((size_t)b * 64 + t) * 64 + l] = f2b(p);
}

// ---------------- cat assembly + p_switch ----------------
__global__ __launch_bounds__(256) void cat_k(
    const float* __restrict__ hd, const float* __restrict__ ce2, const float* __restrict__ cd2,
    const float* __restrict__ W_u, const float* __restrict__ b_u,
    u16* __restrict__ catB, float* __restrict__ p_switch)
{
    const int r = blockIdx.x, tid = threadIdx.x;
    if (r >= NR) {
        for (int j = tid; j < 1536; j += 256) catB[(size_t)r * 1536 + j] = 0;
        return;
    }
    const int t = r >> 4, b = r & 15;
    float partial = 0.f;
    for (int j = tid; j < 1536; j += 256) {
        float v;
        if (j < 512) v = hd[(size_t)r * 512 + j];
        else if (j < 1024) v = ce2[((size_t)b * 64 + t) * 512 + (j - 512)];
        else v = cd2[((size_t)b * 64 + t) * 512 + (j - 1024)];
        catB[(size_t)r * 1536 + j] = f2b(v);
        partial += v * W_u[j];
    }
#pragma unroll
    for (int mk = 1; mk < 64; mk <<= 1) partial += __shfl_xor(partial, mk, 64);
    __shared__ float red[4];
    if ((tid & 63) == 0) red[tid >> 6] = partial;
    __syncthreads();
    if (tid == 0) {
        float u = red[0] + red[1] + red[2] + red[3] + b_u[0];
        p_switch[r] = 1.f / (1.f + __expf(-u));
    }
}

// ---------------- targ logit ----------------
__global__ __launch_bounds__(256) void targ_k(
    const int* __restrict__ tgt, const u16* __restrict__ WembB,
    const u16* __restrict__ WprojT, const u16* __restrict__ catB,
    const float* __restrict__ b_out, float* __restrict__ lt)
{
    const int r = blockIdx.x, tid = threadIdx.x;
    const int v = tgt[r];
    float partial = 0.f;
    for (int k = tid; k < 1536; k += 256) {
        float wk = 0.f;
        const u16* ae = &WembB[(size_t)v * 128];
        const u16* be = &WprojT[(size_t)k * 128];
#pragma unroll 4
        for (int e = 0; e < 128; e++) wk += b2f(ae[e]) * b2f(be[e]);
        float w = b2f(f2b(tanhf(wk)));
        partial += w * b2f(catB[(size_t)r * 1536 + k]);
    }
#pragma unroll
    for (int mk = 1; mk < 64; mk <<= 1) partial += __shfl_xor(partial, mk, 64);
    __shared__ float red[4];
    if ((tid & 63) == 0) red[tid >> 6] = partial;
    __syncthreads();
    if (tid == 0) lt[r] = red[0] + red[1] + red[2] + red[3] + b_out[v];
}

// ---------------- per-row LSE combine (wave per row) ----------------
__global__ __launch_bounds__(256) void rowred_k(
    const float* __restrict__ pmax, const float* __restrict__ psum,
    const float* __restrict__ lt, const float* __restrict__ p_switch,
    const float* __restrict__ copysum, const int* __restrict__ tgt,
    float* __restrict__ terms)
{
    const int r = blockIdx.x * 4 + (threadIdx.x >> 6);
    const int l = threadIdx.x & 63;
    float m = -1e30f, s = 0.f;
    for (int cb = l; cb < NCB; cb += 64) {
        float me = pmax[(size_t)cb * NR + r];
        float se = psum[(size_t)cb * NR + r];
        float M2 = fmaxf(m, me);
        s = s * __expf(m - M2) + se * __expf(me - M2);
        m = M2;
    }
#pragma unroll
    for (int mk = 1; mk < 64; mk <<= 1) {
        float mo = __shfl_xor(m, mk, 64);
        float so = __shfl_xor(s, mk, 64);
        float M2 = fmaxf(m, mo);
        s = s * __expf(m - M2) + so * __expf(mo - M2);
        m = M2;
    }
    if (l == 0) {
        float ps = p_switch[r];
        float tg = (1.f - ps) * __expf(lt[r] - m) / s;
        float tc = ps * copysum[r];
        terms[r] = (tgt[r] != 0) ? -logf(tg + tc + 2e-12f) : 0.f;
    }
}

__global__ __launch_bounds__(256) void final_k(const float* __restrict__ terms, float* __restrict__ out)
{
    const int tid = threadIdx.x;
    float p = 0.f;
    for (int i = tid; i < NR; i += 256) p += terms[i];
#pragma unroll
    for (int mk = 1; mk < 64; mk <<= 1) p += __shfl_xor(p, mk, 64);
    __shared__ float red[4];
    if ((tid & 63) == 0) red[tid >> 6] = p;
    __syncthreads();
    if (tid == 0) out[0] = red[0] + red[1] + red[2] + red[3];
}

// ---------------- host launch ----------------
extern "C" void kernel_launch(void* const* d_in, const int* in_sizes, int n_in,
                              void* d_out, int out_size, void* d_ws, size_t ws_size,
                              hipStream_t stream)
{
    const int*   tgt    = (const int*)d_in[0];
    const float* algn   = (const float*)d_in[2];
    const float* h_e    = (const float*)d_in[3];
    const float* h0     = (const float*)d_in[4];
    const float* c0     = (const float*)d_in[5];
    const float* W_emb  = (const float*)d_in[6];
    const float* W_ih   = (const float*)d_in[7];
    const float* W_hh   = (const float*)d_in[8];
    const float* b_ih   = (const float*)d_in[9];
    const float* b_hh   = (const float*)d_in[10];
    const float* W_ae   = (const float*)d_in[11];
    const float* W_ad   = (const float*)d_in[12];
    const float* W_proj = (const float*)d_in[13];
    const float* W_u    = (const float*)d_in[14];
    const float* b_u    = (const float*)d_in[15];
    const float* b_out  = (const float*)d_in[16];
    (void)in_sizes; (void)n_in; (void)out_size; (void)ws_size;

    char* ws = (char*)d_ws;
    size_t off = 0;
    auto alloc = [&](size_t bytes) -> char* {
        char* p = ws + off;
        off += (bytes + 255) & ~(size_t)255;
        return p;
    };
    u16* wbuf    = (u16*)alloc((size_t)12800 * 1536 * 2);   // also overlaid: attention scratch
    u16* catB    = (u16*)alloc((size_t)1024 * 1536 * 2);
    u16* WprojT  = (u16*)alloc((size_t)1536 * 128 * 2);
    u16* WihB    = (u16*)alloc((size_t)2048 * 128 * 2);
    u16* WhhB    = (u16*)alloc((size_t)2048 * 512 * 2);
    u16* WattnT  = (u16*)alloc((size_t)1024 * 512 * 2);
    u16* WembB   = (u16*)alloc((size_t)NVP * 128 * 2);
    u16* embB    = (u16*)alloc((size_t)NR * 128 * 2);
    u16* hdB     = (u16*)alloc((size_t)NR * 512 * 2);
    u16* hB      = (u16*)alloc((size_t)2 * 8192 * 2);
    float* preGI = (float*)alloc((size_t)NR * 2048 * 4);
    float* hd    = (float*)alloc((size_t)NR * 512 * 4);
    float* c_st  = (float*)alloc((size_t)8192 * 4);
    float* q     = (float*)alloc((size_t)NR * 1024 * 4);
    float* p_sw  = (float*)alloc(NR * 4);
    float* copys = (float*)alloc(NR * 4);
    float* lt    = (float*)alloc(NR * 4);
    float* terms = (float*)alloc(NR * 4);
    float* pmax  = (float*)alloc((size_t)NCB * NR * 4);
    float* psum  = (float*)alloc((size_t)NCB * NR * 4);

    // attention scratch overlaid into wbuf (wbuf used only after cat_k)
    u16* h_eB = wbuf;                      // 16*448*512
    u16* h_eT = h_eB + (size_t)16 * 448 * 512;
    u16* qeB  = h_eT + (size_t)16 * 448 * 512;  // 16*64*512
    u16* qdB  = qeB + (size_t)16 * 64 * 512;
    u16* hdUB = qdB + (size_t)16 * 64 * 512;
    u16* hdT  = hdUB + (size_t)16 * 64 * 512;
    u16* PeB  = hdT + (size_t)16 * 64 * 512;    // 16*64*448
    u16* PdB  = PeB + (size_t)16 * 64 * 448;    // 16*64*64
    float* Se = (float*)(PdB + (size_t)16 * 64 * 64);   // 16*64*448 f32
    float* Sd = Se + (size_t)16 * 64 * 448;             // 16*64*64
    float* ce2 = Sd + (size_t)16 * 64 * 64;             // 16*64*512
    float* cd2 = ce2 + (size_t)16 * 64 * 512;           // 16*64*512

    // prep
    conv_k<<<dim3((2048 * 128 + 255) / 256), 256, 0, stream>>>(W_ih, WihB, 2048 * 128);
    conv_k<<<dim3((2048 * 512 + 255) / 256), 256, 0, stream>>>(W_hh, WhhB, 2048 * 512);
    embpad_k<<<dim3((NVP * 128 + 255) / 256), 256, 0, stream>>>(W_emb, WembB);
    attnT_k<<<dim3((1024 * 512 + 255) / 256), 256, 0, stream>>>(W_ae, W_ad, WattnT);
    projT_k<<<dim3((1536 * 128 + 255) / 256), 256, 0, stream>>>(W_proj, WprojT);
    gather_k<<<dim3((NR * 128 + 255) / 256), 256, 0, stream>>>(W_emb, tgt, embB);
    init_k<<<dim3(32), 256, 0, stream>>>(c0, h0, c_st, hB);
    prep_he_k<<<dim3(7, 16), 256, 0, stream>>>(h_e, h_eB, h_eT);

    // preGI = emb @ W_ih^T + b_ih + b_hh
    gemm64_k<<<dim3(2048 / 64, NR / 64), 256, 0, stream>>>(embB, WihB, 128, 2048, preGI, b_ih, b_hh);

    // LSTM, 60 sequential steps
    for (int t = 0; t < 60; t++) {
        const u16* hin = hB + (size_t)(t & 1) * 8192;
        u16* hout = hB + (size_t)((t & 1) ^ 1) * 8192;
        lstm_step<<<dim3(32), 256, 0, stream>>>(
            WhhB, hin, hout, preGI + (size_t)t * 16 * 2048,
            c_st, hd + (size_t)t * 8192, hdB + (size_t)t * 8192);
    }

    // q = hd @ [W_attn_e | W_attn_d]
    gemm64_k<<<dim3(1024 / 64, NR / 64), 256, 0, stream>>>(hdB, WattnT, 512, 1024, q, nullptr, nullptr);
    qprep_k<<<dim3(64, 16), 256, 0, stream>>>(q, qeB, qdB);
    prep_hd_k<<<dim3(16), 256, 0, stream>>>(hd, hdUB, hdT);

    // scores
    gemm_b_k<<<dim3(7, 1, 16), 256, 0, stream>>>(qeB, 64 * 512, h_eB, 448 * 512, 512, Se, 64 * 448, 448);
    gemm_b_k<<<dim3(1, 1, 16), 256, 0, stream>>>(qdB, 64 * 512, hdUB, 64 * 512, 512, Sd, 64 * 64, 64);
    softmax_e_k<<<dim3(240), 256, 0, stream>>>(Se, algn, PeB, copys);
    softmax_d_k<<<dim3(240), 256, 0, stream>>>(Sd, PdB);
    // PV
    gemm_b_k<<<dim3(8, 1, 16), 256, 0, stream>>>(PeB, 64 * 448, h_eT, 512 * 448, 448, ce2, 64 * 512, 512);
    gemm_b_k<<<dim3(8, 1, 16), 256, 0, stream>>>(PdB, 64 * 64, hdT, 512 * 64, 64, cd2, 64 * 512, 512);

    cat_k<<<dim3(1024), 256, 0, stream>>>(hd, ce2, cd2, W_u, b_u, catB, p_sw);

    // chunked: W_out chunk = tanh(W_emb @ W_proj), then cat @ chunk^T with streaming LSE
    const int vc0s[4] = {0, 12800, 25600, 38400};
    const int nccs[4] = {12800, 12800, 12800, 11904};
    for (int c = 0; c < 4; c++) {
        gemm128_k<1><<<dim3(1536 / 128, nccs[c] / 128), 256, 0, stream>>>(
            WembB + (size_t)vc0s[c] * 128, WprojT, 128, wbuf, 1536, nullptr, nullptr, nullptr, 0);
        gemm128_k<2><<<dim3(nccs[c] / 128, 1024 / 128), 256, 0, stream>>>(
            catB, wbuf, 1536, nullptr, 0, b_out, pmax, psum, vc0s[c]);
    }

    targ_k<<<dim3(NR), 256, 0, stream>>>(tgt, WembB, WprojT, catB, b_out, lt);
    rowred_k<<<dim3(240), 256, 0, stream>>>(pmax, psum, lt, p_sw, copys, tgt, terms);
    final_k<<<dim3(1), 256, 0, stream>>>(terms, (float*)d_out);
}